// Round 1
// baseline (1240.026 us; speedup 1.0000x reference)
//
#include <hip/hip_runtime.h>

#define TT 2048
#define BB 256
#define XX 64
#define HH 128
#define YY 32
#define CHUNK 8
#define NCHUNK (TT/CHUNK)   // 256

// One block per batch row. 256 threads = 4 waves (one per SIMD).
// Thread (wave w, lane l): owns output j = w*32 + (l&31), k-half kh = l>>5.
// W_hh[j, kh*64 .. +64) and W_ih[j, kh*32 .. +32) held in registers.
// h double-buffered in LDS (1 barrier/step); x streamed in 8-step chunks,
// double-buffered, prefetched one chunk ahead.
__global__ __launch_bounds__(256, 1) void rnn_persist_kernel(
    const float* __restrict__ x,
    const float* __restrict__ W_ih,
    const float* __restrict__ W_hh,
    const float* __restrict__ b_ih,
    const float* __restrict__ b_hh,
    const float* __restrict__ W_out,
    const float* __restrict__ b_out,
    float* __restrict__ out)
{
    __shared__ float h_lds[2][HH];
    __shared__ float x_lds[2][CHUNK * XX];

    const int tid  = threadIdx.x;
    const int b    = blockIdx.x;
    const int wv   = tid >> 6;          // 0..3
    const int lane = tid & 63;
    const int kh   = lane >> 5;         // 0 or 1 (k-half)
    const int j    = wv * 32 + (lane & 31);  // 0..127 (output index)

    // ---- weights into registers (one-time, L2-cached across blocks) ----
    float4 whh4[16];
    {
        const float4* p = (const float4*)(W_hh + j * HH + kh * 64);
        #pragma unroll
        for (int k = 0; k < 16; ++k) whh4[k] = p[k];
    }
    float4 wih4[8];
    {
        const float4* p = (const float4*)(W_ih + j * XX + kh * 32);
        #pragma unroll
        for (int k = 0; k < 8; ++k) wih4[k] = p[k];
    }
    const float bs = b_ih[j] + b_hh[j];

    const float* xg = x + (size_t)b * TT * XX;

    // ---- prologue: stage x chunk 0, zero h ----
    if (tid < 128) {
        ((float4*)&x_lds[0][0])[tid] = ((const float4*)xg)[tid];
        h_lds[0][tid] = 0.f;
    }
    __syncthreads();

    int par = 0;  // h read buffer index
    for (int c = 0; c < NCHUNK; ++c) {
        const int buf = c & 1;

        // prefetch next x chunk into registers (write to LDS at chunk end)
        float4 xn;
        const bool pf = (tid < 128) && (c + 1 < NCHUNK);
        if (pf) xn = ((const float4*)(xg + (size_t)(c + 1) * CHUNK * XX))[tid];

        for (int s = 0; s < CHUNK; ++s) {
            const float* xs = &x_lds[buf][s * XX + kh * 32];  // half-wave uniform
            const float* hs = &h_lds[par][kh * 64];           // half-wave uniform
            float a0 = 0.f, a1 = 0.f, a2 = 0.f, a3 = 0.f;
            // input projection partial (32 MACs)
            #pragma unroll
            for (int i = 0; i < 8; ++i) {
                const float4 xv = ((const float4*)xs)[i];
                a0 = fmaf(wih4[i].x, xv.x, a0);
                a1 = fmaf(wih4[i].y, xv.y, a1);
                a2 = fmaf(wih4[i].z, xv.z, a2);
                a3 = fmaf(wih4[i].w, xv.w, a3);
            }
            // recurrent partial (64 MACs)
            #pragma unroll
            for (int k = 0; k < 16; ++k) {
                const float4 hv = ((const float4*)hs)[k];
                a0 = fmaf(whh4[k].x, hv.x, a0);
                a1 = fmaf(whh4[k].y, hv.y, a1);
                a2 = fmaf(whh4[k].z, hv.z, a2);
                a3 = fmaf(whh4[k].w, hv.w, a3);
            }
            float sum = (a0 + a1) + (a2 + a3);
            // combine k-halves: partner lane is lane^32 (same j)
            sum += __shfl_xor(sum, 32, 64);
            sum += bs;
            // tanh(z) = 1 - 2/(exp(2z)+1): saturates to +/-1, no inf/inf
            const float e  = __expf(2.f * sum);
            const float hn = 1.f - 2.f / (e + 1.f);
            // both kh lanes write identical value to same address (benign)
            h_lds[par ^ 1][j] = hn;
            __syncthreads();
            par ^= 1;
        }

        // land the prefetched x chunk; barrier so next chunk sees it
        if (pf) ((float4*)&x_lds[buf ^ 1][0])[tid] = xn;
        __syncthreads();
    }

    // ---- readout: out[b, :] = h_last @ W_out^T + b_out ----
    if (tid < YY) {
        const float* h = h_lds[par];
        const float4* wr = (const float4*)(W_out + tid * HH);
        float r0 = 0.f, r1 = 0.f, r2 = 0.f, r3 = 0.f;
        #pragma unroll
        for (int k = 0; k < 32; ++k) {
            const float4 wvv = wr[k];
            const float4 hv  = ((const float4*)h)[k];
            r0 = fmaf(wvv.x, hv.x, r0);
            r1 = fmaf(wvv.y, hv.y, r1);
            r2 = fmaf(wvv.z, hv.z, r2);
            r3 = fmaf(wvv.w, hv.w, r3);
        }
        out[b * YY + tid] = ((r0 + r1) + (r2 + r3)) + b_out[tid];
    }
}

extern "C" void kernel_launch(void* const* d_in, const int* in_sizes, int n_in,
                              void* d_out, int out_size, void* d_ws, size_t ws_size,
                              hipStream_t stream) {
    const float* x     = (const float*)d_in[0];
    const float* W_ih  = (const float*)d_in[1];
    const float* W_hh  = (const float*)d_in[2];
    const float* b_ih  = (const float*)d_in[3];
    const float* b_hh  = (const float*)d_in[4];
    const float* W_out = (const float*)d_in[5];
    const float* b_out = (const float*)d_in[6];
    float* out = (float*)d_out;

    rnn_persist_kernel<<<BB, 256, 0, stream>>>(x, W_ih, W_hh, b_ih, b_hh,
                                               W_out, b_out, out);
}

// Round 2
// 949.608 us; speedup vs baseline: 1.3058x; 1.3058x over previous
//
#include <hip/hip_runtime.h>

#define TT 2048
#define BB 256
#define XX 64
#define HH 128
#define YY 32
#define CHUNK 32
#define NCHUNK (TT/CHUNK)   // 64

// One block per batch row, 512 threads = 8 waves = 2 waves/SIMD.
// Wave w, lane l: j = w*16 + (l&15)  (output index, 8 waves x 16 = 128)
//                 ks = l>>4 (0..3)   (k-quarter)
// Weights W_hh[j, ks*32..+32) (8 float4) and W_ih[j, ks*16..+16) (4 float4)
// live in registers, pinned via asm so the allocator cannot remat the loads
// (R1: compiler re-loaded weights from global every step -> 1588 cyc/step).
// h double-buffered in LDS; x streamed in 32-step chunks, double-buffered.

static __device__ __forceinline__ void pin4(float4& v) {
    asm volatile("" : "+v"(v.x), "+v"(v.y), "+v"(v.z), "+v"(v.w));
}

__global__ __launch_bounds__(512, 2) void rnn_persist_kernel(
    const float* __restrict__ x,
    const float* __restrict__ W_ih,
    const float* __restrict__ W_hh,
    const float* __restrict__ b_ih,
    const float* __restrict__ b_hh,
    const float* __restrict__ W_out,
    const float* __restrict__ b_out,
    float* __restrict__ out)
{
    __shared__ float h_lds[2][HH];
    __shared__ float x_lds[2][CHUNK * XX];   // 2 x 8 KB

    const int tid  = threadIdx.x;
    const int b    = blockIdx.x;
    const int wv   = tid >> 6;               // 0..7
    const int lane = tid & 63;
    const int ks   = lane >> 4;              // 0..3 (k-quarter)
    const int j    = wv * 16 + (lane & 15);  // 0..127

    // ---- weights into registers, pinned ----
    float4 whh4[8];
    {
        const float4* p = (const float4*)(W_hh + j * HH + ks * 32);
        #pragma unroll
        for (int k = 0; k < 8; ++k) { whh4[k] = p[k]; pin4(whh4[k]); }
    }
    float4 wih4[4];
    {
        const float4* p = (const float4*)(W_ih + j * XX + ks * 16);
        #pragma unroll
        for (int k = 0; k < 4; ++k) { wih4[k] = p[k]; pin4(wih4[k]); }
    }
    const float bs = b_ih[j] + b_hh[j];

    const float* xg = x + (size_t)b * TT * XX;

    // ---- prologue: stage x chunk 0 (512 float4 = 512 threads), zero h ----
    ((float4*)&x_lds[0][0])[tid] = ((const float4*)xg)[tid];
    if (tid < HH) h_lds[0][tid] = 0.f;
    __syncthreads();

    int par = 0;
    for (int c = 0; c < NCHUNK; ++c) {
        const int buf = c & 1;

        // prefetch next x chunk into a register (landed after the chunk)
        float4 xn;
        const bool pf = (c + 1 < NCHUNK);
        if (pf) xn = ((const float4*)(xg + (size_t)(c + 1) * CHUNK * XX))[tid];

        for (int s = 0; s < CHUNK; ++s) {
            // x-projection partial FIRST: independent of h, off critical path
            const float* xs = &x_lds[buf][s * XX + ks * 16];
            float a0 = 0.f, a1 = 0.f, a2 = 0.f, a3 = 0.f;
            #pragma unroll
            for (int i = 0; i < 4; ++i) {
                const float4 xv = ((const float4*)xs)[i];
                a0 = fmaf(wih4[i].x, xv.x, a0);
                a1 = fmaf(wih4[i].y, xv.y, a1);
                a2 = fmaf(wih4[i].z, xv.z, a2);
                a3 = fmaf(wih4[i].w, xv.w, a3);
            }
            // recurrent partial
            const float* hs = &h_lds[par][ks * 32];
            #pragma unroll
            for (int k = 0; k < 8; ++k) {
                const float4 hv = ((const float4*)hs)[k];
                a0 = fmaf(whh4[k].x, hv.x, a0);
                a1 = fmaf(whh4[k].y, hv.y, a1);
                a2 = fmaf(whh4[k].z, hv.z, a2);
                a3 = fmaf(whh4[k].w, hv.w, a3);
            }
            float sum = (a0 + a1) + (a2 + a3);
            // combine the 4 k-quarters: lanes {l, l^16, l^32, l^48} share j
            sum += __shfl_xor(sum, 16, 64);
            sum += __shfl_xor(sum, 32, 64);
            sum += bs;
            // tanh(z) = 1 - 2/(exp2(2z*log2e)+1); rcp is 1-ulp approx
            const float e  = exp2f(sum * 2.885390082f);
            const float r  = __builtin_amdgcn_rcpf(e + 1.f);
            const float hn = fmaf(-2.f, r, 1.f);
            if (ks == 0) h_lds[par ^ 1][j] = hn;
            __syncthreads();
            par ^= 1;
        }

        if (pf) {
            ((float4*)&x_lds[buf ^ 1][0])[tid] = xn;
            __syncthreads();
        }
    }

    // ---- readout: out[b, :] = h_last @ W_out^T + b_out ----
    if (tid < YY) {
        const float* h = h_lds[par];
        const float4* wr = (const float4*)(W_out + tid * HH);
        float r0 = 0.f, r1 = 0.f, r2 = 0.f, r3 = 0.f;
        #pragma unroll
        for (int k = 0; k < 32; ++k) {
            const float4 wvv = wr[k];
            const float4 hv  = ((const float4*)h)[k];
            r0 = fmaf(wvv.x, hv.x, r0);
            r1 = fmaf(wvv.y, hv.y, r1);
            r2 = fmaf(wvv.z, hv.z, r2);
            r3 = fmaf(wvv.w, hv.w, r3);
        }
        out[b * YY + tid] = ((r0 + r1) + (r2 + r3)) + b_out[tid];
    }
}

extern "C" void kernel_launch(void* const* d_in, const int* in_sizes, int n_in,
                              void* d_out, int out_size, void* d_ws, size_t ws_size,
                              hipStream_t stream) {
    const float* x     = (const float*)d_in[0];
    const float* W_ih  = (const float*)d_in[1];
    const float* W_hh  = (const float*)d_in[2];
    const float* b_ih  = (const float*)d_in[3];
    const float* b_hh  = (const float*)d_in[4];
    const float* W_out = (const float*)d_in[5];
    const float* b_out = (const float*)d_in[6];
    float* out = (float*)d_out;

    rnn_persist_kernel<<<BB, 512, 0, stream>>>(x, W_ih, W_hh, b_ih, b_hh,
                                               W_out, b_out, out);
}